// Round 11
// baseline (1180.756 us; speedup 1.0000x reference)
//
#include <hip/hip_runtime.h>
#include <math.h>

typedef float f32x4 __attribute__((ext_vector_type(4)));
typedef __bf16 bf16x8 __attribute__((ext_vector_type(8)));
typedef unsigned short u16x8 __attribute__((ext_vector_type(8)));

__device__ __forceinline__ unsigned short f2bf(float f) {
    union { float f; unsigned int u; } v; v.f = f;
    unsigned int r = v.u + 0x7FFFu + ((v.u >> 16) & 1u);
    return (unsigned short)(r >> 16);
}
__device__ __forceinline__ unsigned short f2bft(float f) {  // truncate (1 VALU op)
    union { float f; unsigned int u; } v; v.f = f;
    return (unsigned short)(v.u >> 16);
}
__device__ __forceinline__ float bf2f(unsigned short u) {
    union { unsigned int u; float f; } v; v.u = ((unsigned int)u) << 16;
    return v.f;
}
__device__ __forceinline__ bf16x8 ld8(const unsigned short* p) {
    union { u16x8 u; bf16x8 b; } c;
    c.u = *(const u16x8*)p;
    return c.b;
}
__device__ __forceinline__ void gload_lds16(const unsigned short* g, unsigned short* l) {
    __builtin_amdgcn_global_load_lds(
        (const __attribute__((address_space(1))) unsigned int*)g,
        (__attribute__((address_space(3))) unsigned int*)l,
        16, 0, 0);
}
// [nrows][32]-short tile, XOR-swizzled chunk layout (0 bank conflicts, R2-verified)
__device__ __forceinline__ int swz_off(int row, int quad) {
    return row * 32 + ((quad ^ ((row >> 1) & 3)) << 3);
}

// ---------------------------------------------------------------------------
// Weight prep R11: dense-write design. Each block owns 32 output rows x 768
// output cols of Wt[N][K]. Reads: 32-col fp32 slab = exactly one 128B line
// per k-row (coalesced). Transpose via padded LDS bf16 buffer [32][776]
// (b16 scatter, 4-way bank conflict, hidden under global loads). Write: 32
// rows x 1536B dense full-line stores — consecutive blocks cover adjacent
// n-panels. W2 (K=3072) split into 4 K-chunks. Grid (288, layers).
__global__ __launch_bounds__(256)
void wprep_k(const float* __restrict__ Wqkv, const float* __restrict__ Wo,
             const float* __restrict__ W1, const float* __restrict__ W2,
             unsigned short* __restrict__ qkvT, unsigned short* __restrict__ woT,
             unsigned short* __restrict__ w1T, unsigned short* __restrict__ w2T) {
    __shared__ unsigned short out[32][776];   // 49664 B; pad->row stride 1552B
    int idx = blockIdx.x;
    size_t ly = blockIdx.y;
    const float* W; unsigned short* Wt; int N, K, n0, kc = 0;
    if (idx < 72)       { W = Wqkv + ly * 768 * 2304; Wt = qkvT + ly * 768 * 2304; N = 2304; K = 768;  n0 = idx * 32; }
    else if (idx < 96)  { W = Wo   + ly * 768 * 768;  Wt = woT  + ly * 768 * 768;  N = 768;  K = 768;  n0 = (idx - 72) * 32; }
    else if (idx < 192) { W = W1   + ly * 768 * 3072; Wt = w1T  + ly * 768 * 3072; N = 3072; K = 768;  n0 = (idx - 96) * 32; }
    else { int j = idx - 192; W = W2 + ly * 3072 * 768; Wt = w2T + ly * 3072 * 768; N = 768; K = 3072; n0 = (j % 24) * 32; kc = (j / 24) * 768; }

    int tid = threadIdx.x;
    const int tx = tid & 31, ty = tid >> 5;   // 32 n-lanes x 8 k-rows
#pragma unroll 4
    for (int i = 0; i < 96; ++i) {
        int k = ty + i * 8;
        out[tx][k] = f2bf(W[(size_t)(kc + k) * N + n0 + tx]);
    }
    __syncthreads();
#pragma unroll
    for (int r = 0; r < 12; ++r) {
        int ci = tid + r * 256;               // 32 rows x 96 u16x8 chunks
        int row = ci / 96, cc = ci % 96;
        u16x8 v = *(const u16x8*)&out[row][cc * 8];
        *(u16x8*)&Wt[(size_t)(n0 + row) * K + kc + cc * 8] = v;
    }
}

// ---------------------------------------------------------------------------
__global__ __launch_bounds__(256)
void posenc_k(const float* __restrict__ x, float* __restrict__ h,
              unsigned short* __restrict__ hb) {
    int idx = blockIdx.x * 256 + threadIdx.x;
    const int TOT = 4 * 1024 * 768;
    if (idx >= TOT) return;
    int d = idx % 768;
    int s = (idx / 768) % 1024;
    int i2 = d >> 1;
    float dv = expf(-(float)(2 * i2) * (9.210340371976184f / 768.0f));
    float ang = (float)s * dv;
    float pe = (d & 1) ? cosf(ang) : sinf(ang);
    float v = x[idx] + pe;
    h[idx] = v;
    hb[idx] = f2bf(v);
}

// ---------------------------------------------------------------------------
// GEMM: C[M,N] = A[M,K](bf16) @ Bt[N,K](bf16)^T (+bias) (+relu), split-K via z.
// QSCALE: multiply columns [0,768) by 0.125*log2(e) after bias (Q pre-scale
// for exp2 softmax; block-uniform since 768 % 128 == 0).
// Output bf16. Single-barrier double-buffered global_load_lds staging.
// (R6 lesson: do NOT reg-stage the A side — global_load_lds is faster.)
template<int RELU, int BIAS, int QSCALE>
__global__ __launch_bounds__(256)
void gemm_k(const unsigned short* __restrict__ A, const unsigned short* __restrict__ Bt,
            const float* __restrict__ bias, unsigned short* __restrict__ Cb,
            int M, int N, int K, int Kc) {
    __shared__ unsigned short As[2][128 * 32];
    __shared__ unsigned short Bs[2][128 * 32];
    const int tid = threadIdx.x;
    const int lane = tid & 63, wave = tid >> 6;
    const int l15 = lane & 15, quad = lane >> 4;
    const int m0 = blockIdx.y * 128, n0 = blockIdx.x * 128;
    const int wr = (wave >> 1) * 64, wc = (wave & 1) * 64;
    const int kstart = blockIdx.z * Kc;
    unsigned short* Cbp = Cb + (size_t)blockIdx.z * M * N;

    const int r0 = wave * 32 + (lane >> 2);
    const int kc0 = lane & 3;

    auto stage = [&](int k0, int bi) {
#pragma unroll
        for (int j = 0; j < 2; ++j) {
            int r = r0 + j * 16;
            int kcl = kc0 ^ ((r >> 1) & 3);
            gload_lds16(A + (size_t)(m0 + r) * K + k0 + kcl * 8,
                        &As[bi][(wave * 32 + j * 16) * 32]);
            gload_lds16(Bt + (size_t)(n0 + r) * K + k0 + kcl * 8,
                        &Bs[bi][(wave * 32 + j * 16) * 32]);
        }
    };

    f32x4 acc[4][4];
#pragma unroll
    for (int i = 0; i < 4; ++i)
#pragma unroll
        for (int j = 0; j < 4; ++j) acc[i][j] = (f32x4){0.f, 0.f, 0.f, 0.f};

    stage(kstart, 0);
    const int nk = Kc / 32;
    for (int t = 0; t < nk; ++t) {
        __syncthreads();
        if (t + 1 < nk) stage(kstart + (t + 1) * 32, (t + 1) & 1);
        const unsigned short* Asb = As[t & 1];
        const unsigned short* Bsb = Bs[t & 1];
        bf16x8 af[4], bfr[4];
#pragma unroll
        for (int mt = 0; mt < 4; ++mt)
            af[mt] = ld8(&Asb[swz_off(wr + mt * 16 + l15, quad)]);
#pragma unroll
        for (int nt = 0; nt < 4; ++nt)
            bfr[nt] = ld8(&Bsb[swz_off(wc + nt * 16 + l15, quad)]);
#pragma unroll
        for (int mt = 0; mt < 4; ++mt)
#pragma unroll
            for (int nt = 0; nt < 4; ++nt)
                acc[mt][nt] = __builtin_amdgcn_mfma_f32_16x16x32_bf16(
                    af[mt], bfr[nt], acc[mt][nt], 0, 0, 0);
    }
    const float scl = (QSCALE && n0 < 768) ? 0.18033688088889765f : 1.0f;
#pragma unroll
    for (int mt = 0; mt < 4; ++mt)
#pragma unroll
        for (int nt = 0; nt < 4; ++nt)
#pragma unroll
            for (int r = 0; r < 4; ++r) {
                int row = m0 + wr + mt * 16 + quad * 4 + r;
                int col = n0 + wc + nt * 16 + l15;
                float v = acc[mt][nt][r];
                if (BIAS) v += bias[col];
                if (QSCALE) v *= scl;
                if (RELU) v = fmaxf(v, 0.f);
                Cbp[(size_t)row * N + col] = f2bf(v);
            }
}

// ---------------------------------------------------------------------------
// V transpose only: qkv V slice -> Vt[B,H,64(d),1024(s)]. grid (S/64, B*H).
__global__ __launch_bounds__(256)
void vt_prep(const unsigned short* __restrict__ qkv, unsigned short* __restrict__ Vt) {
    __shared__ unsigned short t[64][65];
    int bh = blockIdx.y, s0 = blockIdx.x * 64;
    int b = bh / 12, h = bh % 12;
    int tid = threadIdx.x;
    int tx = tid & 63, ty = tid >> 6;
#pragma unroll
    for (int r = 0; r < 16; ++r) {
        int i = ty + r * 4;
        t[i][tx] = qkv[(size_t)(b * 1024 + s0 + i) * 2304 + 1536 + h * 64 + tx];
    }
    __syncthreads();
#pragma unroll
    for (int r = 0; r < 16; ++r) {
        int dd = ty + r * 4;
        Vt[((size_t)bh * 64 + dd) * 1024 + s0 + tx] = t[tx][dd];
    }
}

// ---------------------------------------------------------------------------
// Flash attention, fixed-max exp2 softmax. No split-S (R10-verified): each
// block does all 16 K/V tiles; denominator lacc[r] is lane-local with
// o[cb][r] (both row = quad*4+r) so ctx is written directly.
// Q,K read directly from qkv (row stride 2304); Q pre-scaled by 0.125*log2(e).
// Single-barrier double-buffered K/V staging (R7-verified).
// LDS 40 KB: Qs/Ps 8K | Ks dbuf 2x8K | Vs dbuf 2x8K. Grid (16, 48) = 768 blk.
__global__ __launch_bounds__(256)
void flash_k(const unsigned short* __restrict__ QKV, const unsigned short* __restrict__ Vt,
             unsigned short* __restrict__ ctx) {
    const int S = 1024, HD = 64;
    int bh = blockIdx.y, b = bh / 12, h = bh % 12;
    int q0 = blockIdx.x * 64;
    const unsigned short* Qp = QKV + (size_t)(b * 1024 + q0) * 2304 + h * 64;
    const unsigned short* Kp = QKV + (size_t)(b * 1024) * 2304 + 768 + h * 64;
    const unsigned short* Vp = Vt + (size_t)bh * HD * S;

    __shared__ unsigned short sm[20480];     // 40960 B
    unsigned short* Qs = sm;                  // [0,4096) shorts; aliased by Ps

    int tid = threadIdx.x, lane = tid & 63, wave = tid >> 6;
    int l15 = lane & 15, quad = lane >> 4;
    const int rl0 = lane >> 2, c0 = lane & 3;

    // stage Q once (row R = khalf*64 + qrow)
#pragma unroll
    for (int j = 0; j < 2; ++j) {
        int R = wave * 32 + j * 16 + rl0;
        int khalf = R >> 6, grow = R & 63;
        int lch = c0 ^ ((R >> 1) & 3);
        gload_lds16(Qp + (size_t)grow * 2304 + khalf * 32 + lch * 8,
                    &Qs[(wave * 32 + j * 16) * 32]);
    }
    __syncthreads();
    bf16x8 qa0 = ld8(&Qs[swz_off(wave * 16 + l15, quad)]);
    bf16x8 qa1 = ld8(&Qs[swz_off(64 + wave * 16 + l15, quad)]);

    auto stageKV = [&](int kt, int bi) {
        unsigned short* Ksb = sm + 4096 + bi * 4096;
        unsigned short* Vsb = sm + 12288 + bi * 4096;
#pragma unroll
        for (int j = 0; j < 2; ++j) {
            int R = wave * 32 + j * 16 + rl0;
            int khalf = R >> 6, grow = R & 63;
            int lch = c0 ^ ((R >> 1) & 3);
            gload_lds16(Kp + (size_t)(kt * 64 + grow) * 2304 + khalf * 32 + lch * 8,
                        &Ksb[(wave * 32 + j * 16) * 32]);
            gload_lds16(Vp + (size_t)grow * S + kt * 64 + khalf * 32 + lch * 8,
                        &Vsb[(wave * 32 + j * 16) * 32]);
        }
    };

    f32x4 o[4];
#pragma unroll
    for (int i = 0; i < 4; ++i) o[i] = (f32x4){0.f, 0.f, 0.f, 0.f};
    f32x4 lacc = (f32x4){0.f, 0.f, 0.f, 0.f};
    bf16x8 ones;
    {
        union { u16x8 u; bf16x8 b; } c;
#pragma unroll
        for (int j = 0; j < 8; ++j) c.u[j] = 0x3F80;  // bf16 1.0
        ones = c.b;
    }
    unsigned short* Pw = sm + wave * 1024;   // 16 rows x 64, quad-XOR swizzled

    stageKV(0, 0);
    for (int i = 0; i < 16; ++i) {
        __syncthreads();   // buf[i&1] staged; prev-iter reads + prologue Q reads done
        if (i < 15) stageKV(i + 1, (i + 1) & 1);
        const unsigned short* Ks = sm + 4096 + (i & 1) * 4096;
        const unsigned short* Vs = sm + 12288 + (i & 1) * 4096;

        f32x4 sc[4];
#pragma unroll
        for (int cb = 0; cb < 4; ++cb) {
            bf16x8 kb0 = ld8(&Ks[swz_off(cb * 16 + l15, quad)]);
            bf16x8 kb1 = ld8(&Ks[swz_off(64 + cb * 16 + l15, quad)]);
            f32x4 z = (f32x4){0.f, 0.f, 0.f, 0.f};
            z = __builtin_amdgcn_mfma_f32_16x16x32_bf16(qa0, kb0, z, 0, 0, 0);
            z = __builtin_amdgcn_mfma_f32_16x16x32_bf16(qa1, kb1, z, 0, 0, 0);
            sc[cb] = z;
        }
        // exp2 (log2e+scale folded into Q), truncate to bf16, store to Ps
#pragma unroll
        for (int cb = 0; cb < 4; ++cb)
#pragma unroll
            for (int r = 0; r < 4; ++r)
                Pw[(quad * 4 + r) * 64 + ((cb * 16 + l15) ^ (quad << 4))] =
                    f2bft(__builtin_amdgcn_exp2f(sc[cb][r]));
        bf16x8 pa0 = ld8(&Pw[l15 * 64 + ((quad * 8) ^ ((l15 >> 2) << 4))]);
        bf16x8 pa1 = ld8(&Pw[l15 * 64 + ((32 + quad * 8) ^ ((l15 >> 2) << 4))]);
        lacc = __builtin_amdgcn_mfma_f32_16x16x32_bf16(pa0, ones, lacc, 0, 0, 0);
        lacc = __builtin_amdgcn_mfma_f32_16x16x32_bf16(pa1, ones, lacc, 0, 0, 0);
#pragma unroll
        for (int cb = 0; cb < 4; ++cb) {
            bf16x8 vb0 = ld8(&Vs[swz_off(cb * 16 + l15, quad)]);
            bf16x8 vb1 = ld8(&Vs[swz_off(64 + cb * 16 + l15, quad)]);
            o[cb] = __builtin_amdgcn_mfma_f32_16x16x32_bf16(pa0, vb0, o[cb], 0, 0, 0);
            o[cb] = __builtin_amdgcn_mfma_f32_16x16x32_bf16(pa1, vb1, o[cb], 0, 0, 0);
        }
    }
    // lane-local divide: lacc[r] is the full denominator for row quad*4+r
    float inv[4];
#pragma unroll
    for (int r = 0; r < 4; ++r) inv[r] = 1.0f / lacc[r];
#pragma unroll
    for (int cb = 0; cb < 4; ++cb)
#pragma unroll
        for (int r = 0; r < 4; ++r) {
            int row = q0 + wave * 16 + quad * 4 + r;
            ctx[((size_t)(b * 1024 + row)) * 768 + h * 64 + cb * 16 + l15] =
                f2bf(o[cb][r] * inv[r]);
        }
}

// ---------------------------------------------------------------------------
// LayerNorm over D=768. NPART>0: residual = X + sum(bf16 partials) + proj-bias.
template<int NPART, int WBF16>
__global__ __launch_bounds__(256)
void ln_k(const float* __restrict__ X, const unsigned short* __restrict__ P,
          const float* __restrict__ pb,
          const float* __restrict__ g, const float* __restrict__ bta,
          float* __restrict__ Yf, unsigned short* __restrict__ Yb) {
    const int D = 768;
    const size_t MD = (size_t)4096 * 768;
    int row = blockIdx.x;
    int tid = threadIdx.x;
    const float* x = X + (size_t)row * D;
    float v[3];
    float s = 0.f, s2 = 0.f;
#pragma unroll
    for (int i = 0; i < 3; ++i) {
        int c = i * 256 + tid;
        float t = x[c];
        if (NPART > 0) {
            float r = pb[c];
#pragma unroll
            for (int pi = 0; pi < NPART; ++pi)
                r += bf2f(P[MD * pi + (size_t)row * D + c]);
            t += r;
        }
        v[i] = t;
        s += t;
        s2 += t * t;
    }
#pragma unroll
    for (int off = 1; off < 64; off <<= 1) {
        s += __shfl_xor(s, off);
        s2 += __shfl_xor(s2, off);
    }
    __shared__ float rs[4], rs2[4];
    int wave = tid >> 6, lane = tid & 63;
    if (lane == 0) { rs[wave] = s; rs2[wave] = s2; }
    __syncthreads();
    s = rs[0] + rs[1] + rs[2] + rs[3];
    s2 = rs2[0] + rs2[1] + rs2[2] + rs2[3];
    float mu = s * (1.f / 768.f);
    float var = s2 * (1.f / 768.f) - mu * mu;
    float rstd = rsqrtf(var + 1e-5f);
#pragma unroll
    for (int i = 0; i < 3; ++i) {
        int c = i * 256 + tid;
        float y = (v[i] - mu) * rstd * g[c] + bta[c];
        Yf[(size_t)row * D + c] = y;
        if (WBF16) Yb[(size_t)row * D + c] = f2bf(y);
    }
}

// ---------------------------------------------------------------------------
extern "C" void kernel_launch(void* const* d_in, const int* in_sizes, int n_in,
                              void* d_out, int out_size, void* d_ws, size_t ws_size,
                              hipStream_t stream) {
    const float* x    = (const float*)d_in[0];
    const float* Wqkv = (const float*)d_in[1];
    const float* bqkv = (const float*)d_in[2];
    const float* Wo   = (const float*)d_in[3];
    const float* bo   = (const float*)d_in[4];
    const float* ln1g = (const float*)d_in[5];
    const float* ln1b = (const float*)d_in[6];
    const float* W1   = (const float*)d_in[7];
    const float* b1   = (const float*)d_in[8];
    const float* W2   = (const float*)d_in[9];
    const float* b2   = (const float*)d_in[10];
    const float* ln2g = (const float*)d_in[11];
    const float* ln2b = (const float*)d_in[12];
    const float* lnfg = (const float*)d_in[13];
    const float* lnfb = (const float*)d_in[14];

    const int B = 4, S = 1024, D = 768, H = 12, F = 3072, L = 6;
    const int M = B * S;  // 4096

    const int WL = (ws_size >= (size_t)200 * 1024 * 1024) ? 6 : 1;

    char* p = (char*)d_ws;
    auto alloc = [&](size_t bytes) -> char* {
        char* r = p;
        p += (bytes + 255) & ~(size_t)255;
        return r;
    };
    float* h             = (float*)alloc((size_t)M * D * 4);
    unsigned short* tmp  = (unsigned short*)alloc((size_t)2 * M * D * 2); // split-K partials (z=0,1)
    unsigned short* hb   = (unsigned short*)alloc((size_t)M * D * 2);
    unsigned short* act  = (unsigned short*)alloc((size_t)M * F * 2); // qkv / ffn1 union
    unsigned short* Vtb  = (unsigned short*)alloc((size_t)M * D * 2);
    unsigned short* ctx  = (unsigned short*)alloc((size_t)M * D * 2);
    unsigned short* wqkvT = (unsigned short*)alloc((size_t)WL * 3 * D * D * 2);
    unsigned short* woT   = (unsigned short*)alloc((size_t)WL * D * D * 2);
    unsigned short* w1T   = (unsigned short*)alloc((size_t)WL * D * F * 2);
    unsigned short* w2T   = (unsigned short*)alloc((size_t)WL * D * F * 2);
    unsigned short* qkvb = act;
    unsigned short* f1b  = act;

    posenc_k<<<(M * D) / 256, 256, 0, stream>>>(x, h, hb);
    if (WL == 6)
        wprep_k<<<dim3(288, 6), 256, 0, stream>>>(Wqkv, Wo, W1, W2,
                                                  wqkvT, woT, w1T, w2T);

    for (int l = 0; l < L; ++l) {
        if (WL == 1)
            wprep_k<<<dim3(288, 1), 256, 0, stream>>>(
                Wqkv + (size_t)l * D * 3 * D, Wo + (size_t)l * D * D,
                W1 + (size_t)l * D * F, W2 + (size_t)l * F * D,
                wqkvT, woT, w1T, w2T);
        size_t lo = (WL == 6) ? (size_t)l : 0;
        const unsigned short* qT  = wqkvT + lo * 3 * D * D;
        const unsigned short* oT  = woT   + lo * D * D;
        const unsigned short* f1T = w1T   + lo * D * F;
        const unsigned short* f2T = w2T   + lo * D * F;

        // qkv = hb @ WqkvT + bqkv (bf16); Q columns pre-scaled for exp2 softmax
        gemm_k<0, 1, 1><<<dim3(3 * D / 128, M / 128, 1), 256, 0, stream>>>(
            hb, qT, bqkv + (size_t)l * 3 * D, qkvb, M, 3 * D, D, D);
        vt_prep<<<dim3(S / 64, B * H), 256, 0, stream>>>(qkvb, Vtb);
        // flash writes ctx directly (no split-S, no combine)
        flash_k<<<dim3(S / 64, B * H), 256, 0, stream>>>(qkvb, Vtb, ctx);
        // attn out proj: split-K=2, bf16 partials (no bias)
        gemm_k<0, 0, 0><<<dim3(D / 128, M / 128, 2), 256, 0, stream>>>(
            ctx, oT, nullptr, tmp, M, D, D, D / 2);
        ln_k<2, 1><<<M, 256, 0, stream>>>(h, tmp, bo + (size_t)l * D,
                                          ln1g + (size_t)l * D, ln1b + (size_t)l * D,
                                          h, hb);
        // ffn1 (relu, bf16 out)
        gemm_k<1, 1, 0><<<dim3(F / 128, M / 128, 1), 256, 0, stream>>>(
            hb, f1T, b1 + (size_t)l * F, f1b, M, F, D, D);
        // ffn2: split-K=2, bf16 partials (no bias)
        gemm_k<0, 0, 0><<<dim3(D / 128, M / 128, 2), 256, 0, stream>>>(
            f1b, f2T, nullptr, tmp, M, D, F, F / 2);
        ln_k<2, 1><<<M, 256, 0, stream>>>(h, tmp, b2 + (size_t)l * D,
                                          ln2g + (size_t)l * D, ln2b + (size_t)l * D,
                                          h, hb);
    }
    ln_k<0, 0><<<M, 256, 0, stream>>>(h, nullptr, nullptr, lnfg, lnfb,
                                      (float*)d_out, nullptr);
}

// Round 12
// 1163.584 us; speedup vs baseline: 1.0148x; 1.0148x over previous
//
#include <hip/hip_runtime.h>
#include <math.h>

typedef float f32x4 __attribute__((ext_vector_type(4)));
typedef __bf16 bf16x8 __attribute__((ext_vector_type(8)));
typedef unsigned short u16x8 __attribute__((ext_vector_type(8)));

__device__ __forceinline__ unsigned short f2bf(float f) {
    union { float f; unsigned int u; } v; v.f = f;
    unsigned int r = v.u + 0x7FFFu + ((v.u >> 16) & 1u);
    return (unsigned short)(r >> 16);
}
__device__ __forceinline__ unsigned short f2bft(float f) {  // truncate (1 VALU op)
    union { float f; unsigned int u; } v; v.f = f;
    return (unsigned short)(v.u >> 16);
}
__device__ __forceinline__ float bf2f(unsigned short u) {
    union { unsigned int u; float f; } v; v.u = ((unsigned int)u) << 16;
    return v.f;
}
__device__ __forceinline__ bf16x8 ld8(const unsigned short* p) {
    union { u16x8 u; bf16x8 b; } c;
    c.u = *(const u16x8*)p;
    return c.b;
}
__device__ __forceinline__ void gload_lds16(const unsigned short* g, unsigned short* l) {
    __builtin_amdgcn_global_load_lds(
        (const __attribute__((address_space(1))) unsigned int*)g,
        (__attribute__((address_space(3))) unsigned int*)l,
        16, 0, 0);
}
// [nrows][32]-short tile, XOR-swizzled chunk layout (0 bank conflicts, R2-verified)
__device__ __forceinline__ int swz_off(int row, int quad) {
    return row * 32 + ((quad ^ ((row >> 1) & 3)) << 3);
}

// ---------------------------------------------------------------------------
// Fused weight prep (R2-verified 32x32): W[K][N] fp32 -> Wt[N][K] bf16.
// grid.x = 6912 tiles, grid.y = layer. ~73 us. FLOOR: three structurally
// different designs (R2 scalar 32x32, R4 vectorized 64x64, R11 dense-write)
// all land at 2.0-2.4 TB/s — transpose memory-system floor. Do not retry.
__global__ __launch_bounds__(256)
void wprep_k(const float* __restrict__ Wqkv, const float* __restrict__ Wo,
             const float* __restrict__ W1, const float* __restrict__ W2,
             unsigned short* __restrict__ qkvT, unsigned short* __restrict__ woT,
             unsigned short* __restrict__ w1T, unsigned short* __restrict__ w2T) {
    __shared__ float tile[32][33];
    int bid = blockIdx.x;
    size_t ly = blockIdx.y;
    const float* W; unsigned short* Wt; int K, N, idx;
    if (bid < 1728)      { W = Wqkv + ly * 768 * 2304; Wt = qkvT + ly * 768 * 2304; K = 768;  N = 2304; idx = bid; }
    else if (bid < 2304) { W = Wo   + ly * 768 * 768;  Wt = woT  + ly * 768 * 768;  K = 768;  N = 768;  idx = bid - 1728; }
    else if (bid < 4608) { W = W1   + ly * 768 * 3072; Wt = w1T  + ly * 768 * 3072; K = 768;  N = 3072; idx = bid - 2304; }
    else                 { W = W2   + ly * 3072 * 768; Wt = w2T  + ly * 3072 * 768; K = 3072; N = 768;  idx = bid - 4608; }
    int ntile = N / 32;
    int n0 = (idx % ntile) * 32, k0 = (idx / ntile) * 32;
    int tx = threadIdx.x & 31, ty = threadIdx.x >> 5;
#pragma unroll
    for (int i = 0; i < 4; ++i) {
        int k = ty + i * 8;
        tile[k][tx] = W[(size_t)(k0 + k) * N + n0 + tx];
    }
    __syncthreads();
#pragma unroll
    for (int i = 0; i < 4; ++i) {
        int n = ty + i * 8;
        Wt[(size_t)(n0 + n) * K + k0 + tx] = f2bf(tile[tx][n]);
    }
}

// ---------------------------------------------------------------------------
__global__ __launch_bounds__(256)
void posenc_k(const float* __restrict__ x, float* __restrict__ h,
              unsigned short* __restrict__ hb) {
    int idx = blockIdx.x * 256 + threadIdx.x;
    const int TOT = 4 * 1024 * 768;
    if (idx >= TOT) return;
    int d = idx % 768;
    int s = (idx / 768) % 1024;
    int i2 = d >> 1;
    float dv = expf(-(float)(2 * i2) * (9.210340371976184f / 768.0f));
    float ang = (float)s * dv;
    float pe = (d & 1) ? cosf(ang) : sinf(ang);
    float v = x[idx] + pe;
    h[idx] = v;
    hb[idx] = f2bf(v);
}

// ---------------------------------------------------------------------------
// GEMM: C[M,N] = A[M,K](bf16) @ Bt[N,K](bf16)^T (+bias) (+relu), split-K via z.
// QSCALE: multiply columns [0,768) by 0.125*log2(e) after bias (Q pre-scale
// for exp2 softmax; block-uniform since 768 % 128 == 0).
// Output bf16. Single-barrier double-buffered global_load_lds staging.
// (R6 lesson: do NOT reg-stage the A side — global_load_lds is faster.)
template<int RELU, int BIAS, int QSCALE>
__global__ __launch_bounds__(256)
void gemm_k(const unsigned short* __restrict__ A, const unsigned short* __restrict__ Bt,
            const float* __restrict__ bias, unsigned short* __restrict__ Cb,
            int M, int N, int K, int Kc) {
    __shared__ unsigned short As[2][128 * 32];
    __shared__ unsigned short Bs[2][128 * 32];
    const int tid = threadIdx.x;
    const int lane = tid & 63, wave = tid >> 6;
    const int l15 = lane & 15, quad = lane >> 4;
    const int m0 = blockIdx.y * 128, n0 = blockIdx.x * 128;
    const int wr = (wave >> 1) * 64, wc = (wave & 1) * 64;
    const int kstart = blockIdx.z * Kc;
    unsigned short* Cbp = Cb + (size_t)blockIdx.z * M * N;

    const int r0 = wave * 32 + (lane >> 2);
    const int kc0 = lane & 3;

    auto stage = [&](int k0, int bi) {
#pragma unroll
        for (int j = 0; j < 2; ++j) {
            int r = r0 + j * 16;
            int kcl = kc0 ^ ((r >> 1) & 3);
            gload_lds16(A + (size_t)(m0 + r) * K + k0 + kcl * 8,
                        &As[bi][(wave * 32 + j * 16) * 32]);
            gload_lds16(Bt + (size_t)(n0 + r) * K + k0 + kcl * 8,
                        &Bs[bi][(wave * 32 + j * 16) * 32]);
        }
    };

    f32x4 acc[4][4];
#pragma unroll
    for (int i = 0; i < 4; ++i)
#pragma unroll
        for (int j = 0; j < 4; ++j) acc[i][j] = (f32x4){0.f, 0.f, 0.f, 0.f};

    stage(kstart, 0);
    const int nk = Kc / 32;
    for (int t = 0; t < nk; ++t) {
        __syncthreads();
        if (t + 1 < nk) stage(kstart + (t + 1) * 32, (t + 1) & 1);
        const unsigned short* Asb = As[t & 1];
        const unsigned short* Bsb = Bs[t & 1];
        bf16x8 af[4], bfr[4];
#pragma unroll
        for (int mt = 0; mt < 4; ++mt)
            af[mt] = ld8(&Asb[swz_off(wr + mt * 16 + l15, quad)]);
#pragma unroll
        for (int nt = 0; nt < 4; ++nt)
            bfr[nt] = ld8(&Bsb[swz_off(wc + nt * 16 + l15, quad)]);
#pragma unroll
        for (int mt = 0; mt < 4; ++mt)
#pragma unroll
            for (int nt = 0; nt < 4; ++nt)
                acc[mt][nt] = __builtin_amdgcn_mfma_f32_16x16x32_bf16(
                    af[mt], bfr[nt], acc[mt][nt], 0, 0, 0);
    }
    const float scl = (QSCALE && n0 < 768) ? 0.18033688088889765f : 1.0f;
#pragma unroll
    for (int mt = 0; mt < 4; ++mt)
#pragma unroll
        for (int nt = 0; nt < 4; ++nt)
#pragma unroll
            for (int r = 0; r < 4; ++r) {
                int row = m0 + wr + mt * 16 + quad * 4 + r;
                int col = n0 + wc + nt * 16 + l15;
                float v = acc[mt][nt][r];
                if (BIAS) v += bias[col];
                if (QSCALE) v *= scl;
                if (RELU) v = fmaxf(v, 0.f);
                Cbp[(size_t)row * N + col] = f2bf(v);
            }
}

// ---------------------------------------------------------------------------
// V transpose only: qkv V slice -> Vt[B,H,64(d),1024(s)]. grid (S/64, B*H).
__global__ __launch_bounds__(256)
void vt_prep(const unsigned short* __restrict__ qkv, unsigned short* __restrict__ Vt) {
    __shared__ unsigned short t[64][65];
    int bh = blockIdx.y, s0 = blockIdx.x * 64;
    int b = bh / 12, h = bh % 12;
    int tid = threadIdx.x;
    int tx = tid & 63, ty = tid >> 6;
#pragma unroll
    for (int r = 0; r < 16; ++r) {
        int i = ty + r * 4;
        t[i][tx] = qkv[(size_t)(b * 1024 + s0 + i) * 2304 + 1536 + h * 64 + tx];
    }
    __syncthreads();
#pragma unroll
    for (int r = 0; r < 16; ++r) {
        int dd = ty + r * 4;
        Vt[((size_t)bh * 64 + dd) * 1024 + s0 + tx] = t[tx][dd];
    }
}

// ---------------------------------------------------------------------------
// Flash attention, fixed-max exp2 softmax. No split-S (R10-verified): each
// block does all 16 K/V tiles; denominator lacc[r] is lane-local with
// o[cb][r] (both row = quad*4+r) so ctx is written directly.
// Q,K read directly from qkv (row stride 2304); Q pre-scaled by 0.125*log2(e).
// Single-barrier double-buffered K/V staging (R7-verified).
// LDS 40 KB: Qs/Ps 8K | Ks dbuf 2x8K | Vs dbuf 2x8K. Grid (16, 48) = 768 blk.
__global__ __launch_bounds__(256)
void flash_k(const unsigned short* __restrict__ QKV, const unsigned short* __restrict__ Vt,
             unsigned short* __restrict__ ctx) {
    const int S = 1024, HD = 64;
    int bh = blockIdx.y, b = bh / 12, h = bh % 12;
    int q0 = blockIdx.x * 64;
    const unsigned short* Qp = QKV + (size_t)(b * 1024 + q0) * 2304 + h * 64;
    const unsigned short* Kp = QKV + (size_t)(b * 1024) * 2304 + 768 + h * 64;
    const unsigned short* Vp = Vt + (size_t)bh * HD * S;

    __shared__ unsigned short sm[20480];     // 40960 B
    unsigned short* Qs = sm;                  // [0,4096) shorts; aliased by Ps

    int tid = threadIdx.x, lane = tid & 63, wave = tid >> 6;
    int l15 = lane & 15, quad = lane >> 4;
    const int rl0 = lane >> 2, c0 = lane & 3;

    // stage Q once (row R = khalf*64 + qrow)
#pragma unroll
    for (int j = 0; j < 2; ++j) {
        int R = wave * 32 + j * 16 + rl0;
        int khalf = R >> 6, grow = R & 63;
        int lch = c0 ^ ((R >> 1) & 3);
        gload_lds16(Qp + (size_t)grow * 2304 + khalf * 32 + lch * 8,
                    &Qs[(wave * 32 + j * 16) * 32]);
    }
    __syncthreads();
    bf16x8 qa0 = ld8(&Qs[swz_off(wave * 16 + l15, quad)]);
    bf16x8 qa1 = ld8(&Qs[swz_off(64 + wave * 16 + l15, quad)]);

    auto stageKV = [&](int kt, int bi) {
        unsigned short* Ksb = sm + 4096 + bi * 4096;
        unsigned short* Vsb = sm + 12288 + bi * 4096;
#pragma unroll
        for (int j = 0; j < 2; ++j) {
            int R = wave * 32 + j * 16 + rl0;
            int khalf = R >> 6, grow = R & 63;
            int lch = c0 ^ ((R >> 1) & 3);
            gload_lds16(Kp + (size_t)(kt * 64 + grow) * 2304 + khalf * 32 + lch * 8,
                        &Ksb[(wave * 32 + j * 16) * 32]);
            gload_lds16(Vp + (size_t)grow * S + kt * 64 + khalf * 32 + lch * 8,
                        &Vsb[(wave * 32 + j * 16) * 32]);
        }
    };

    f32x4 o[4];
#pragma unroll
    for (int i = 0; i < 4; ++i) o[i] = (f32x4){0.f, 0.f, 0.f, 0.f};
    f32x4 lacc = (f32x4){0.f, 0.f, 0.f, 0.f};
    bf16x8 ones;
    {
        union { u16x8 u; bf16x8 b; } c;
#pragma unroll
        for (int j = 0; j < 8; ++j) c.u[j] = 0x3F80;  // bf16 1.0
        ones = c.b;
    }
    unsigned short* Pw = sm + wave * 1024;   // 16 rows x 64, quad-XOR swizzled

    stageKV(0, 0);
    for (int i = 0; i < 16; ++i) {
        __syncthreads();   // buf[i&1] staged; prev-iter reads + prologue Q reads done
        if (i < 15) stageKV(i + 1, (i + 1) & 1);
        const unsigned short* Ks = sm + 4096 + (i & 1) * 4096;
        const unsigned short* Vs = sm + 12288 + (i & 1) * 4096;

        f32x4 sc[4];
#pragma unroll
        for (int cb = 0; cb < 4; ++cb) {
            bf16x8 kb0 = ld8(&Ks[swz_off(cb * 16 + l15, quad)]);
            bf16x8 kb1 = ld8(&Ks[swz_off(64 + cb * 16 + l15, quad)]);
            f32x4 z = (f32x4){0.f, 0.f, 0.f, 0.f};
            z = __builtin_amdgcn_mfma_f32_16x16x32_bf16(qa0, kb0, z, 0, 0, 0);
            z = __builtin_amdgcn_mfma_f32_16x16x32_bf16(qa1, kb1, z, 0, 0, 0);
            sc[cb] = z;
        }
        // exp2 (log2e+scale folded into Q), truncate to bf16, store to Ps
#pragma unroll
        for (int cb = 0; cb < 4; ++cb)
#pragma unroll
            for (int r = 0; r < 4; ++r)
                Pw[(quad * 4 + r) * 64 + ((cb * 16 + l15) ^ (quad << 4))] =
                    f2bft(__builtin_amdgcn_exp2f(sc[cb][r]));
        bf16x8 pa0 = ld8(&Pw[l15 * 64 + ((quad * 8) ^ ((l15 >> 2) << 4))]);
        bf16x8 pa1 = ld8(&Pw[l15 * 64 + ((32 + quad * 8) ^ ((l15 >> 2) << 4))]);
        lacc = __builtin_amdgcn_mfma_f32_16x16x32_bf16(pa0, ones, lacc, 0, 0, 0);
        lacc = __builtin_amdgcn_mfma_f32_16x16x32_bf16(pa1, ones, lacc, 0, 0, 0);
#pragma unroll
        for (int cb = 0; cb < 4; ++cb) {
            bf16x8 vb0 = ld8(&Vs[swz_off(cb * 16 + l15, quad)]);
            bf16x8 vb1 = ld8(&Vs[swz_off(64 + cb * 16 + l15, quad)]);
            o[cb] = __builtin_amdgcn_mfma_f32_16x16x32_bf16(pa0, vb0, o[cb], 0, 0, 0);
            o[cb] = __builtin_amdgcn_mfma_f32_16x16x32_bf16(pa1, vb1, o[cb], 0, 0, 0);
        }
    }
    // lane-local divide: lacc[r] is the full denominator for row quad*4+r
    float inv[4];
#pragma unroll
    for (int r = 0; r < 4; ++r) inv[r] = 1.0f / lacc[r];
#pragma unroll
    for (int cb = 0; cb < 4; ++cb)
#pragma unroll
        for (int r = 0; r < 4; ++r) {
            int row = q0 + wave * 16 + quad * 4 + r;
            ctx[((size_t)(b * 1024 + row)) * 768 + h * 64 + cb * 16 + l15] =
                f2bf(o[cb][r] * inv[r]);
        }
}

// ---------------------------------------------------------------------------
// LayerNorm over D=768. NPART>0: residual = X + sum(bf16 partials) + proj-bias.
template<int NPART, int WBF16>
__global__ __launch_bounds__(256)
void ln_k(const float* __restrict__ X, const unsigned short* __restrict__ P,
          const float* __restrict__ pb,
          const float* __restrict__ g, const float* __restrict__ bta,
          float* __restrict__ Yf, unsigned short* __restrict__ Yb) {
    const int D = 768;
    const size_t MD = (size_t)4096 * 768;
    int row = blockIdx.x;
    int tid = threadIdx.x;
    const float* x = X + (size_t)row * D;
    float v[3];
    float s = 0.f, s2 = 0.f;
#pragma unroll
    for (int i = 0; i < 3; ++i) {
        int c = i * 256 + tid;
        float t = x[c];
        if (NPART > 0) {
            float r = pb[c];
#pragma unroll
            for (int pi = 0; pi < NPART; ++pi)
                r += bf2f(P[MD * pi + (size_t)row * D + c]);
            t += r;
        }
        v[i] = t;
        s += t;
        s2 += t * t;
    }
#pragma unroll
    for (int off = 1; off < 64; off <<= 1) {
        s += __shfl_xor(s, off);
        s2 += __shfl_xor(s2, off);
    }
    __shared__ float rs[4], rs2[4];
    int wave = tid >> 6, lane = tid & 63;
    if (lane == 0) { rs[wave] = s; rs2[wave] = s2; }
    __syncthreads();
    s = rs[0] + rs[1] + rs[2] + rs[3];
    s2 = rs2[0] + rs2[1] + rs2[2] + rs2[3];
    float mu = s * (1.f / 768.f);
    float var = s2 * (1.f / 768.f) - mu * mu;
    float rstd = rsqrtf(var + 1e-5f);
#pragma unroll
    for (int i = 0; i < 3; ++i) {
        int c = i * 256 + tid;
        float y = (v[i] - mu) * rstd * g[c] + bta[c];
        Yf[(size_t)row * D + c] = y;
        if (WBF16) Yb[(size_t)row * D + c] = f2bf(y);
    }
}

// ---------------------------------------------------------------------------
extern "C" void kernel_launch(void* const* d_in, const int* in_sizes, int n_in,
                              void* d_out, int out_size, void* d_ws, size_t ws_size,
                              hipStream_t stream) {
    const float* x    = (const float*)d_in[0];
    const float* Wqkv = (const float*)d_in[1];
    const float* bqkv = (const float*)d_in[2];
    const float* Wo   = (const float*)d_in[3];
    const float* bo   = (const float*)d_in[4];
    const float* ln1g = (const float*)d_in[5];
    const float* ln1b = (const float*)d_in[6];
    const float* W1   = (const float*)d_in[7];
    const float* b1   = (const float*)d_in[8];
    const float* W2   = (const float*)d_in[9];
    const float* b2   = (const float*)d_in[10];
    const float* ln2g = (const float*)d_in[11];
    const float* ln2b = (const float*)d_in[12];
    const float* lnfg = (const float*)d_in[13];
    const float* lnfb = (const float*)d_in[14];

    const int B = 4, S = 1024, D = 768, H = 12, F = 3072, L = 6;
    const int M = B * S;  // 4096

    const int WL = (ws_size >= (size_t)200 * 1024 * 1024) ? 6 : 1;

    char* p = (char*)d_ws;
    auto alloc = [&](size_t bytes) -> char* {
        char* r = p;
        p += (bytes + 255) & ~(size_t)255;
        return r;
    };
    float* h             = (float*)alloc((size_t)M * D * 4);
    unsigned short* tmp  = (unsigned short*)alloc((size_t)4 * M * D * 2); // split-K partials (z=0..3)
    unsigned short* hb   = (unsigned short*)alloc((size_t)M * D * 2);
    unsigned short* act  = (unsigned short*)alloc((size_t)M * F * 2); // qkv / ffn1 union
    unsigned short* Vtb  = (unsigned short*)alloc((size_t)M * D * 2);
    unsigned short* ctx  = (unsigned short*)alloc((size_t)M * D * 2);
    unsigned short* wqkvT = (unsigned short*)alloc((size_t)WL * 3 * D * D * 2);
    unsigned short* woT   = (unsigned short*)alloc((size_t)WL * D * D * 2);
    unsigned short* w1T   = (unsigned short*)alloc((size_t)WL * D * F * 2);
    unsigned short* w2T   = (unsigned short*)alloc((size_t)WL * D * F * 2);
    unsigned short* qkvb = act;
    unsigned short* f1b  = act;

    posenc_k<<<(M * D) / 256, 256, 0, stream>>>(x, h, hb);
    if (WL == 6)
        wprep_k<<<dim3(6912, 6), 256, 0, stream>>>(Wqkv, Wo, W1, W2,
                                                   wqkvT, woT, w1T, w2T);

    for (int l = 0; l < L; ++l) {
        if (WL == 1)
            wprep_k<<<dim3(6912, 1), 256, 0, stream>>>(
                Wqkv + (size_t)l * D * 3 * D, Wo + (size_t)l * D * D,
                W1 + (size_t)l * D * F, W2 + (size_t)l * F * D,
                wqkvT, woT, w1T, w2T);
        size_t lo = (WL == 6) ? (size_t)l : 0;
        const unsigned short* qT  = wqkvT + lo * 3 * D * D;
        const unsigned short* oT  = woT   + lo * D * D;
        const unsigned short* f1T = w1T   + lo * D * F;
        const unsigned short* f2T = w2T   + lo * D * F;

        // qkv = hb @ WqkvT + bqkv (bf16); Q columns pre-scaled for exp2 softmax
        gemm_k<0, 1, 1><<<dim3(3 * D / 128, M / 128, 1), 256, 0, stream>>>(
            hb, qT, bqkv + (size_t)l * 3 * D, qkvb, M, 3 * D, D, D);
        vt_prep<<<dim3(S / 64, B * H), 256, 0, stream>>>(qkvb, Vtb);
        // flash writes ctx directly (no split-S, no combine)
        flash_k<<<dim3(S / 64, B * H), 256, 0, stream>>>(qkvb, Vtb, ctx);
        // attn out proj: split-K=4 (A/B vs R10's z=2), bf16 partials (no bias)
        gemm_k<0, 0, 0><<<dim3(D / 128, M / 128, 4), 256, 0, stream>>>(
            ctx, oT, nullptr, tmp, M, D, D, D / 4);
        ln_k<4, 1><<<M, 256, 0, stream>>>(h, tmp, bo + (size_t)l * D,
                                          ln1g + (size_t)l * D, ln1b + (size_t)l * D,
                                          h, hb);
        // ffn1 (relu, bf16 out)
        gemm_k<1, 1, 0><<<dim3(F / 128, M / 128, 1), 256, 0, stream>>>(
            hb, f1T, b1 + (size_t)l * F, f1b, M, F, D, D);
        // ffn2: split-K=4 (A/B vs R10's z=2), bf16 partials (no bias)
        gemm_k<0, 0, 0><<<dim3(D / 128, M / 128, 4), 256, 0, stream>>>(
            f1b, f2T, nullptr, tmp, M, D, F, F / 4);
        ln_k<4, 1><<<M, 256, 0, stream>>>(h, tmp, b2 + (size_t)l * D,
                                          ln2g + (size_t)l * D, ln2b + (size_t)l * D,
                                          h, hb);
    }
    ln_k<0, 0><<<M, 256, 0, stream>>>(h, nullptr, nullptr, lnfg, lnfb,
                                      (float*)d_out, nullptr);
}